// Round 14
// baseline (758.670 us; speedup 1.0000x reference)
//
#include <hip/hip_runtime.h>

#define D 128
#define NLAYERS 3
#define BN_EPS 1e-5f
#define NPART 8

typedef short bf16x8 __attribute__((ext_vector_type(8)));
typedef float f32x4 __attribute__((ext_vector_type(4)));

__device__ __forceinline__ unsigned short f2bf(float f) {
    unsigned int u = __float_as_uint(f);
    u += 0x7FFFu + ((u >> 16) & 1u);   // round-to-nearest-even
    return (unsigned short)(u >> 16);
}
__device__ __forceinline__ float bf2f(unsigned short b) {
    return __uint_as_float(((unsigned int)b) << 16);
}
__device__ __forceinline__ float bf_lo(unsigned int u) {
    return __uint_as_float(u << 16);
}
__device__ __forceinline__ float bf_hi(unsigned int u) {
    return __uint_as_float(u & 0xFFFF0000u);
}

// ---------------- setup kernels ----------------

// zero cnt8 + gcnt + stats in one dispatch
__global__ void k_zero(int* __restrict__ cnt8, int* __restrict__ gcnt,
                       int* __restrict__ stats, int N8, int G, int S) {
    int i = blockIdx.x * blockDim.x + threadIdx.x;
    if (i < N8) cnt8[i] = 0;
    else if (i < N8 + G) gcnt[i - N8] = 0;
    else if (i < N8 + G + S) stats[i - N8 - G] = 0;
}

// merged: partitioned edge histogram + batch histogram + x->bf16 convert
__global__ void k_hist_xb(const int* __restrict__ dst, const int* __restrict__ batch,
                          const float* __restrict__ x,
                          int* __restrict__ cnt8, int* __restrict__ gcnt,
                          unsigned short* __restrict__ fb, int E, int N, int n8,
                          int perPart) {
    int i = blockIdx.x * blockDim.x + threadIdx.x;
    if (i < E) {
        int p = i / perPart;
        atomicAdd(&cnt8[(size_t)p * N + dst[i]], 1);
    } else if (i < E + N) {
        atomicAdd(&gcnt[batch[i - E]], 1);
    } else {
        int j = i - E - N;
        if (j < n8) {
            const float4 a = ((const float4*)x)[j * 2];
            const float4 b = ((const float4*)x)[j * 2 + 1];
            uint4 p;
            p.x = (unsigned int)f2bf(a.x) | ((unsigned int)f2bf(a.y) << 16);
            p.y = (unsigned int)f2bf(a.z) | ((unsigned int)f2bf(a.w) << 16);
            p.z = (unsigned int)f2bf(b.x) | ((unsigned int)f2bf(b.y) << 16);
            p.w = (unsigned int)f2bf(b.z) | ((unsigned int)f2bf(b.w) << 16);
            ((uint4*)fb)[j] = p;
        }
    }
}

// partial sums of PADDED total counts; also computes dinv and zeroes dummy hb row
__global__ void k_scan_partial(const int* __restrict__ cnt8, int* __restrict__ bsum,
                               float* __restrict__ dinv, unsigned short* __restrict__ hb,
                               int N) {
    __shared__ int sh[256];
    int b = blockIdx.x, t = threadIdx.x;
    int base = b * 1024 + t * 4;
    int s = 0;
#pragma unroll
    for (int i = 0; i < 4; ++i) {
        int idx = base + i;
        if (idx < N) {
            int cv = 0;
#pragma unroll
            for (int p = 0; p < NPART; ++p) cv += cnt8[(size_t)p * N + idx];
            dinv[idx] = rsqrtf((float)(cv + 1));   // +1 self loop
            s += (cv + 3) & ~3;
        }
    }
    if (b == 0 && t < D) hb[(size_t)N * D + t] = 0;
    sh[t] = s;
    for (int ofs = 128; ofs > 0; ofs >>= 1) {
        __syncthreads();
        if (t < ofs) sh[t] += sh[t + ofs];
    }
    __syncthreads();
    if (t == 0) bsum[b] = sh[0];
}

// merged: block 0 = exclusive scan of block sums; block 1 = graph-count scan
__global__ void k_scan_small_g(const int* __restrict__ bsum, int* __restrict__ bbase, int nb,
                               const int* __restrict__ gcnt, int* __restrict__ goff,
                               int G, int N) {
    __shared__ int sh[256];
    int t = threadIdx.x;
    if (blockIdx.x == 0) {
        int v = (t < nb) ? bsum[t] : 0;
        sh[t] = v;
        __syncthreads();
        for (int ofs = 1; ofs < 256; ofs <<= 1) {
            int vv = (t >= ofs) ? sh[t - ofs] : 0;
            __syncthreads();
            sh[t] += vv;
            __syncthreads();
        }
        bbase[t] = sh[t] - v;   // exclusive
    } else {
        int base = t * 4;
        int v[4]; int s = 0;
#pragma unroll
        for (int i = 0; i < 4; ++i) { v[i] = (base + i < G) ? gcnt[base + i] : 0; s += v[i]; }
        sh[t] = s;
        __syncthreads();
        for (int ofs = 1; ofs < 256; ofs <<= 1) {
            int vv = (t >= ofs) ? sh[t - ofs] : 0;
            __syncthreads();
            sh[t] += vv;
            __syncthreads();
        }
        int o = sh[t] - s;
#pragma unroll
        for (int i = 0; i < 4; ++i) {
            int idx = base + i;
            if (idx < G) { goff[idx] = o; o += v[i]; }
        }
        if (t == 255) goff[G] = N;
    }
}

// scan apply: writes roff, per-partition cursors cur8[p][v] = roff[v]+prefix,
// and the per-node CSR pad slots (dummy index N).
__global__ void k_scan_apply(const int* __restrict__ cnt8, const int* __restrict__ bbase,
                             int* __restrict__ roff, int* __restrict__ cur8,
                             int* __restrict__ csr, int N) {
    __shared__ int sh[256];
    int b = blockIdx.x, t = threadIdx.x;
    int base = b * 1024 + t * 4;
    int cp[4][NPART];
    int vr[4], v[4]; int s = 0;
#pragma unroll
    for (int i = 0; i < 4; ++i) {
        int idx = base + i;
        int cv = 0;
        if (idx < N) {
#pragma unroll
            for (int p = 0; p < NPART; ++p) { cp[i][p] = cnt8[(size_t)p * N + idx]; cv += cp[i][p]; }
        } else {
#pragma unroll
            for (int p = 0; p < NPART; ++p) cp[i][p] = 0;
        }
        vr[i] = cv;
        v[i] = (cv + 3) & ~3;
        s += v[i];
    }
    sh[t] = s;
    __syncthreads();
    for (int ofs = 1; ofs < 256; ofs <<= 1) {
        int vv = (t >= ofs) ? sh[t - ofs] : 0;
        __syncthreads();
        sh[t] += vv;
        __syncthreads();
    }
    int o = bbase[b] + sh[t] - s;
#pragma unroll
    for (int i = 0; i < 4; ++i) {
        int idx = base + i;
        if (idx < N) {
            roff[idx] = o;
            int pf = o;
#pragma unroll
            for (int p = 0; p < NPART; ++p) { cur8[(size_t)p * N + idx] = pf; pf += cp[i][p]; }
            for (int q = vr[i]; q < v[i]; ++q) csr[o + q] = N;   // pads
            o += v[i];
            if (idx == N - 1) roff[N] = o;
        }
    }
}

__global__ void k_fill(const int* __restrict__ src, const int* __restrict__ dst,
                       int* __restrict__ cur8, int* __restrict__ csr, int E, int N,
                       int perPart) {
    int i = blockIdx.x * blockDim.x + threadIdx.x;
    if (i < E) {
        int p = i / perPart;
        int pos = atomicAdd(&cur8[(size_t)p * N + dst[i]], 1);
        csr[pos] = src[i];
    }
}

// Merged pack + fold + BN-finalize. a/c derived in-kernel from prev stats.
__global__ void k_packfold(const float* __restrict__ W, const float* __restrict__ rW,
                           const float* __restrict__ gam, const float* __restrict__ bet,
                           const float* __restrict__ stats, const float* __restrict__ rb,
                           unsigned short* __restrict__ Wp,
                           float* __restrict__ cwA, float* __restrict__ crb,
                           int first, float invN) {
    if (blockIdx.x < 128) {
        int idx = blockIdx.x * 256 + threadIdx.x;       // 0..32767
        int m = idx >> 14;
        int i = idx & 16383;
        int k = i >> 7, col = i & 127;
        float a = 1.f;
        if (!first) {
            float mean = stats[k] * invN;
            float var = stats[D + k] * invN - mean * mean;
            a = gam[k] * rsqrtf(var + BN_EPS);
        }
        const float* src = m ? rW : W;
        float v = a * src[i];
        int frag = ((k >> 5) << 3) + (col >> 4);
        int lane = (((k & 31) >> 3) << 4) + (col & 15);
        int j = k & 7;
        Wp[(m << 14) + frag * 512 + lane * 8 + j] = f2bf(v);
    } else {
        __shared__ float csh[128];
        int t = threadIdx.x;  // 256
        if (t < D) {
            float c = 0.f;
            if (!first) {
                float mean = stats[t] * invN;
                float var = stats[D + t] * invN - mean * mean;
                float a = gam[t] * rsqrtf(var + BN_EPS);
                c = bet[t] - mean * a;
            }
            csh[t] = c;
        }
        __syncthreads();
        if (t < D) {
            float s = 0.f;
            for (int k = 0; k < D; ++k) s += csh[k] * W[k * D + t];
            cwA[t] = s;
        } else {
            int j = t - D;
            float s = rb[j];
            for (int k = 0; k < D; ++k) s += csh[k] * rW[k * D + j];
            crb[j] = s;
        }
    }
}

// ---------------- MFMA GEMM, 64-row tiles, one GEMM per block ----------------
__global__ __launch_bounds__(256) void k_gemm_mfma(
    const unsigned short* __restrict__ fb,
    const unsigned short* __restrict__ Wp,    // [2][16384] packed frags
    const float* __restrict__ add0, const float* __restrict__ add1,
    const float* __restrict__ dinv,
    unsigned short* __restrict__ hb, unsigned short* __restrict__ rbuf, int N) {
    __shared__ unsigned short As[64 * 128];    // 16 KB, XOR-swizzled
    __shared__ unsigned short Wb[128 * 128];   // 32 KB, linear frag layout
    const int t = threadIdx.x;
    const int m = blockIdx.y;
    const int rowbase = blockIdx.x * 64;
    const unsigned short* wp = Wp + (m << 14);

#pragma unroll
    for (int i = 0; i < 4; ++i) {
        int ch = t + i * 256;
        int row = ch >> 4, slot = ch & 15;
        uint4 v = make_uint4(0, 0, 0, 0);
        int gr = rowbase + row;
        if (gr < N) v = *(const uint4*)(fb + (size_t)gr * D + slot * 8);
        *(uint4*)((char*)As + row * 256 + ((slot ^ (row & 7)) << 4)) = v;
    }
#pragma unroll
    for (int i = 0; i < 8; ++i) {
        int ch = t + i * 256;
        *(uint4*)((char*)Wb + ch * 16) = *(const uint4*)((const char*)wp + ch * 16);
    }
    __syncthreads();

    const int wave = t >> 6, l = t & 63;
    const int wrow = wave * 16;
    const int lg = l >> 4, lc = l & 15;
    const int n0 = wrow + lc;
    const int g0 = rowbase + n0;
    const int f0 = lg * 4;
    const int half = lg & 1;

    f32x4 acc[8];
#pragma unroll
    for (int cf = 0; cf < 8; ++cf) acc[cf] = (f32x4){0.f, 0.f, 0.f, 0.f};

#pragma unroll
    for (int ks = 0; ks < 4; ++ks) {
        const int s = ks * 4 + lg;
        bf16x8 a0 = *(const bf16x8*)((const char*)As + n0 * 256 + ((s ^ (n0 & 7)) << 4));
#pragma unroll
        for (int cf = 0; cf < 8; ++cf) {
            bf16x8 b = *(const bf16x8*)((const char*)Wb + ((ks * 8 + cf) * 64 + l) * 16);
            acc[cf] = __builtin_amdgcn_mfma_f32_16x16x32_bf16(b, a0, acc[cf], 0, 0, 0);
        }
    }

    __syncthreads();   // As consumed -> reuse as epilogue buffer

    if (m == 0) {
        const float dv0 = (g0 < N) ? dinv[g0] : 0.f;
#pragma unroll
        for (int cf = 0; cf < 8; ++cf) {
            const int fx = cf * 16 + f0;
            const float4 va = *(const float4*)(add0 + fx);
            const int slot = cf * 2 + (lg >> 1);
            uint2 p0;
            p0.x = (unsigned int)f2bf((acc[cf][0] + va.x) * dv0) |
                   ((unsigned int)f2bf((acc[cf][1] + va.y) * dv0) << 16);
            p0.y = (unsigned int)f2bf((acc[cf][2] + va.z) * dv0) |
                   ((unsigned int)f2bf((acc[cf][3] + va.w) * dv0) << 16);
            *(uint2*)((char*)As + n0 * 256 + ((slot ^ (n0 & 7)) << 4) + half * 8) = p0;
        }
    } else {
#pragma unroll
        for (int cf = 0; cf < 8; ++cf) {
            const int fx = cf * 16 + f0;
            const float4 va = *(const float4*)(add1 + fx);
            const int slot = cf * 2 + (lg >> 1);
            uint2 p0;
            p0.x = (unsigned int)f2bf(fmaxf(acc[cf][0] + va.x, 0.f)) |
                   ((unsigned int)f2bf(fmaxf(acc[cf][1] + va.y, 0.f)) << 16);
            p0.y = (unsigned int)f2bf(fmaxf(acc[cf][2] + va.z, 0.f)) |
                   ((unsigned int)f2bf(fmaxf(acc[cf][3] + va.w, 0.f)) << 16);
            *(uint2*)((char*)As + n0 * 256 + ((slot ^ (n0 & 7)) << 4) + half * 8) = p0;
        }
    }

    __syncthreads();

    unsigned short* __restrict__ dstp = (m == 0) ? hb : rbuf;
#pragma unroll
    for (int i = 0; i < 4; ++i) {
        int ch = t + i * 256;
        int row = ch >> 4, sl = ch & 15;
        int gr = rowbase + row;
        if (gr < N) {
            uint4 v = *(const uint4*)((const char*)As + row * 256 + ((sl ^ (row & 7)) << 4));
            *(uint4*)(dstp + (size_t)gr * D + sl * 8) = v;
        }
    }
}

// ---------------- aggregation + residual + BN stats ----------------
__global__ __launch_bounds__(256) void k_agg(
    const unsigned short* __restrict__ hb, const unsigned short* __restrict__ resb,
    unsigned short* __restrict__ fbout,
    const int* __restrict__ roff, const int* __restrict__ csr,
    const float* __restrict__ dinv, const float* __restrict__ bias,
    float* __restrict__ stats, int N, int half) {
    const int tid = threadIdx.x;
    const int lane = tid & 63;
    const int g = lane >> 4;           // edge slot within quad
    const int li = lane & 15;          // 16-lane column group
    const int cs = li * 8;             // 8 bf16 columns per lane
    const int wid = (blockIdx.x * blockDim.x + tid) >> 6;
    const int nw = (gridDim.x * blockDim.x) >> 6;

    float bv[8];
#pragma unroll
    for (int k = 0; k < 8; ++k) bv[k] = bias[cs + k];

    float s8[8], q8[8];
#pragma unroll
    for (int k = 0; k < 8; ++k) { s8[k] = 0.f; q8[k] = 0.f; }

    for (int p = wid; p < half; p += nw) {
        const int vA = p;
        const int vB = p + half;
        const bool hasB = (vB < N);
        const int begA = roff[vA];
        const int qA = (roff[vA + 1] - begA) >> 2;
        int begB = begA, qB = 0;
        if (hasB) { begB = roff[vB]; qB = (roff[vB + 1] - begB) >> 2; }

        float accA[8], accB[8];
#pragma unroll
        for (int k = 0; k < 8; ++k) { accA[k] = 0.f; accB[k] = 0.f; }

        const int mq = (qA > qB) ? qA : qB;
        for (int i = 0; i < mq; i += 2) {
            int jA0 = i < qA ? i : (qA - 1); jA0 = jA0 < 0 ? 0 : jA0;
            int jA1 = (i + 1) < qA ? (i + 1) : (qA - 1); jA1 = jA1 < 0 ? 0 : jA1;
            int jB0 = i < qB ? i : (qB - 1); jB0 = jB0 < 0 ? 0 : jB0;
            int jB1 = (i + 1) < qB ? (i + 1) : (qB - 1); jB1 = jB1 < 0 ? 0 : jB1;
            const int4 a40 = *(const int4*)(csr + begA + jA0 * 4);
            const int4 a41 = *(const int4*)(csr + begA + jA1 * 4);
            const int4 b40 = *(const int4*)(csr + begB + jB0 * 4);
            const int4 b41 = *(const int4*)(csr + begB + jB1 * 4);
            int ua0 = (g == 0) ? a40.x : (g == 1) ? a40.y : (g == 2) ? a40.z : a40.w;
            int ua1 = (g == 0) ? a41.x : (g == 1) ? a41.y : (g == 2) ? a41.z : a41.w;
            int ub0 = (g == 0) ? b40.x : (g == 1) ? b40.y : (g == 2) ? b40.z : b40.w;
            int ub1 = (g == 0) ? b41.x : (g == 1) ? b41.y : (g == 2) ? b41.z : b41.w;
            ua0 = (i < qA) ? ua0 : N;
            ua1 = (i + 1 < qA) ? ua1 : N;
            ub0 = (i < qB) ? ub0 : N;
            ub1 = (i + 1 < qB) ? ub1 : N;
            const uint4 ga0 = *(const uint4*)(hb + (size_t)ua0 * D + cs);
            const uint4 ga1 = *(const uint4*)(hb + (size_t)ua1 * D + cs);
            const uint4 gb0 = *(const uint4*)(hb + (size_t)ub0 * D + cs);
            const uint4 gb1 = *(const uint4*)(hb + (size_t)ub1 * D + cs);
            accA[0] += bf_lo(ga0.x) + bf_lo(ga1.x); accA[1] += bf_hi(ga0.x) + bf_hi(ga1.x);
            accA[2] += bf_lo(ga0.y) + bf_lo(ga1.y); accA[3] += bf_hi(ga0.y) + bf_hi(ga1.y);
            accA[4] += bf_lo(ga0.z) + bf_lo(ga1.z); accA[5] += bf_hi(ga0.z) + bf_hi(ga1.z);
            accA[6] += bf_lo(ga0.w) + bf_lo(ga1.w); accA[7] += bf_hi(ga0.w) + bf_hi(ga1.w);
            accB[0] += bf_lo(gb0.x) + bf_lo(gb1.x); accB[1] += bf_hi(gb0.x) + bf_hi(gb1.x);
            accB[2] += bf_lo(gb0.y) + bf_lo(gb1.y); accB[3] += bf_hi(gb0.y) + bf_hi(gb1.y);
            accB[4] += bf_lo(gb0.z) + bf_lo(gb1.z); accB[5] += bf_hi(gb0.z) + bf_hi(gb1.z);
            accB[6] += bf_lo(gb0.w) + bf_lo(gb1.w); accB[7] += bf_hi(gb0.w) + bf_hi(gb1.w);
        }

#pragma unroll
        for (int k = 0; k < 8; ++k) {
            accA[k] += __shfl_xor(accA[k], 16);
            accA[k] += __shfl_xor(accA[k], 32);
            accB[k] += __shfl_xor(accB[k], 16);
            accB[k] += __shfl_xor(accB[k], 32);
        }

        // ---- epilogue node A ----
        {
            const float dv = dinv[vA];
            const uint4 hs = *(const uint4*)(hb + (size_t)vA * D + cs);
            const uint4 rr = *(const uint4*)(resb + (size_t)vA * D + cs);
            float ox[8];
            ox[0] = (accA[0] + bf_lo(hs.x)) * dv + bv[0] + bf_lo(rr.x);
            ox[1] = (accA[1] + bf_hi(hs.x)) * dv + bv[1] + bf_hi(rr.x);
            ox[2] = (accA[2] + bf_lo(hs.y)) * dv + bv[2] + bf_lo(rr.y);
            ox[3] = (accA[3] + bf_hi(hs.y)) * dv + bv[3] + bf_hi(rr.y);
            ox[4] = (accA[4] + bf_lo(hs.z)) * dv + bv[4] + bf_lo(rr.z);
            ox[5] = (accA[5] + bf_hi(hs.z)) * dv + bv[5] + bf_hi(rr.z);
            ox[6] = (accA[6] + bf_lo(hs.w)) * dv + bv[6] + bf_lo(rr.w);
            ox[7] = (accA[7] + bf_hi(hs.w)) * dv + bv[7] + bf_hi(rr.w);
            if (g == 0) {
                uint4 pk;
                pk.x = (unsigned int)f2bf(ox[0]) | ((unsigned int)f2bf(ox[1]) << 16);
                pk.y = (unsigned int)f2bf(ox[2]) | ((unsigned int)f2bf(ox[3]) << 16);
                pk.z = (unsigned int)f2bf(ox[4]) | ((unsigned int)f2bf(ox[5]) << 16);
                pk.w = (unsigned int)f2bf(ox[6]) | ((unsigned int)f2bf(ox[7]) << 16);
                *(uint4*)(fbout + (size_t)vA * D + cs) = pk;
#pragma unroll
                for (int k = 0; k < 8; ++k) { s8[k] += ox[k]; q8[k] += ox[k] * ox[k]; }
            }
        }
        // ---- epilogue node B ----
        if (hasB) {
            const float dv = dinv[vB];
            const uint4 hs = *(const uint4*)(hb + (size_t)vB * D + cs);
            const uint4 rr = *(const uint4*)(resb + (size_t)vB * D + cs);
            float ox[8];
            ox[0] = (accB[0] + bf_lo(hs.x)) * dv + bv[0] + bf_lo(rr.x);
            ox[1] = (accB[1] + bf_hi(hs.x)) * dv + bv[1] + bf_hi(rr.x);
            ox[2] = (accB[2] + bf_lo(hs.y)) * dv + bv[2] + bf_lo(rr.y);
            ox[3] = (accB[3] + bf_hi(hs.y)) * dv + bv[3] + bf_hi(rr.y);
            ox[4] = (accB[4] + bf_lo(hs.z)) * dv + bv[4] + bf_lo(rr.z);
            ox[5] = (accB[5] + bf_hi(hs.z)) * dv + bv[5] + bf_hi(rr.z);
            ox[6] = (accB[6] + bf_lo(hs.w)) * dv + bv[6] + bf_lo(rr.w);
            ox[7] = (accB[7] + bf_hi(hs.w)) * dv + bv[7] + bf_hi(rr.w);
            if (g == 0) {
                uint4 pk;
                pk.x = (unsigned int)f2bf(ox[0]) | ((unsigned int)f2bf(ox[1]) << 16);
                pk.y = (unsigned int)f2bf(ox[2]) | ((unsigned int)f2bf(ox[3]) << 16);
                pk.z = (unsigned int)f2bf(ox[4]) | ((unsigned int)f2bf(ox[5]) << 16);
                pk.w = (unsigned int)f2bf(ox[6]) | ((unsigned int)f2bf(ox[7]) << 16);
                *(uint4*)(fbout + (size_t)vB * D + cs) = pk;
#pragma unroll
                for (int k = 0; k < 8; ++k) { s8[k] += ox[k]; q8[k] += ox[k] * ox[k]; }
            }
        }
    }

    // block-level BN-stats reduction: lanes g==0 hold valid partials
    __shared__ float sred[4][16][8];
    __shared__ float qred[4][16][8];
    const int w = tid >> 6;
    if (g == 0) {
#pragma unroll
        for (int k = 0; k < 8; ++k) { sred[w][li][k] = s8[k]; qred[w][li][k] = q8[k]; }
    }
    __syncthreads();
    if (tid < D) {
        const int col = tid;
        float ts = 0.f, tq = 0.f;
#pragma unroll
        for (int ww = 0; ww < 4; ++ww) {
            ts += sred[ww][col >> 3][col & 7];
            tq += qred[ww][col >> 3][col & 7];
        }
        atomicAdd(&stats[col], ts);
        atomicAdd(&stats[D + col], tq);
    }
}

// pool with embedded final BN: a,c computed per-block from last stats
__global__ void k_pool(const unsigned short* __restrict__ fb, const int* __restrict__ goff,
                       const float* __restrict__ gam, const float* __restrict__ bet,
                       const float* __restrict__ stats, float invN,
                       float* __restrict__ out) {
    int g = blockIdx.x, t = threadIdx.x;  // 128 threads
    float mean = stats[t] * invN;
    float var = stats[D + t] * invN - mean * mean;
    float a = gam[t] * rsqrtf(var + BN_EPS);
    float c = bet[t] - mean * a;
    int beg = goff[g], end = goff[g + 1];
    float acc = 0.f;
    for (int v = beg; v < end; ++v) acc += bf2f(fb[(size_t)v * D + t]);
    out[(size_t)g * D + t] = acc * a + (float)(end - beg) * c;
}

// ---------------- launcher ----------------

extern "C" void kernel_launch(void* const* d_in, const int* in_sizes, int n_in,
                              void* d_out, int out_size, void* d_ws, size_t ws_size,
                              hipStream_t stream) {
    const float* x      = (const float*)d_in[0];
    const int*   ei     = (const int*)d_in[1];
    const int*   batch  = (const int*)d_in[2];
    const float* Ws     = (const float*)d_in[3];
    const float* bs     = (const float*)d_in[4];
    const float* rWs    = (const float*)d_in[5];
    const float* rbs    = (const float*)d_in[6];
    const float* gammas = (const float*)d_in[7];
    const float* betas  = (const float*)d_in[8];
    float* out = (float*)d_out;

    const int N = in_sizes[2];
    const int E = in_sizes[1] / 2;
    const int G = out_size / D;
    const int* src = ei;
    const int* dst = ei + E;
    const int EP = E + 4 * N + 8;   // padded-CSR upper bound (+2 quad guard)
    const int half = (N + 1) >> 1;
    const float invN = 1.0f / (float)N;
    const int n8 = N * (D / 8);
    const int perPart = (E + NPART - 1) / NPART;

    char* ws = (char*)d_ws;
    size_t off = 0;
    auto alloc = [&](size_t bytes) -> char* {
        char* p = ws + off;
        off += (bytes + 255) & ~(size_t)255;
        return p;
    };
    unsigned short* hb = (unsigned short*)alloc((size_t)(N + 1) * D * 2);
    unsigned short* fb = (unsigned short*)alloc((size_t)N * D * 2);
    unsigned short* rbuf = (unsigned short*)alloc((size_t)N * D * 2);
    int*   csr  = (int*)alloc((size_t)EP * 4);
    int*   roff = (int*)alloc((size_t)(N + 1) * 4);
    int*   cur8 = (int*)alloc((size_t)NPART * N * 4);
    int*   cnt8 = (int*)alloc((size_t)NPART * N * 4);
    float* dinv = (float*)alloc((size_t)N * 4);
    int*   gcnt = (int*)alloc((size_t)G * 4);
    int*   goff = (int*)alloc((size_t)(G + 1) * 4);
    int*   bsum = (int*)alloc(256 * 4);
    int*   bbase= (int*)alloc(256 * 4);
    float* stats= (float*)alloc((size_t)NLAYERS * 2 * D * 4);
    unsigned short* Wp = (unsigned short*)alloc((size_t)2 * D * D * 2);
    float* cwA  = (float*)alloc(D * 4);
    float* crb  = (float*)alloc(D * 4);
    (void)ws_size;

    const int S = NLAYERS * 2 * D;
    const int N8 = NPART * N;
    k_zero<<<(N8 + G + S + 255) / 256, 256, 0, stream>>>(cnt8, gcnt, (int*)stats, N8, G, S);
    k_hist_xb<<<(E + N + n8 + 255) / 256, 256, 0, stream>>>(dst, batch, x, cnt8, gcnt,
                                                            fb, E, N, n8, perPart);

    int nb = (N + 1023) / 1024;
    k_scan_partial<<<nb, 256, 0, stream>>>(cnt8, bsum, dinv, hb, N);
    k_scan_small_g<<<2, 256, 0, stream>>>(bsum, bbase, nb, gcnt, goff, G, N);
    k_scan_apply<<<nb, 256, 0, stream>>>(cnt8, bbase, roff, cur8, csr, N);
    k_fill<<<(E + 255) / 256, 256, 0, stream>>>(src, dst, cur8, csr, E, N, perPart);

    dim3 ggrid((N + 63) / 64, 2);
    for (int l = 0; l < NLAYERS; ++l) {
        const float* W  = Ws + (size_t)l * D * D;
        const float* rW = rWs + (size_t)l * D * D;
        const float* gamP = gammas + (size_t)(l > 0 ? l - 1 : 0) * D;
        const float* betP = betas + (size_t)(l > 0 ? l - 1 : 0) * D;
        const float* stP  = stats + (size_t)(l > 0 ? l - 1 : 0) * 2 * D;

        k_packfold<<<129, 256, 0, stream>>>(W, rW, gamP, betP, stP,
                                            rbs + (size_t)l * D,
                                            Wp, cwA, crb, (l == 0) ? 1 : 0, invN);

        k_gemm_mfma<<<ggrid, 256, 0, stream>>>(fb, Wp, cwA, crb, dinv,
                                               hb, rbuf, N);
        k_agg<<<4096, 256, 0, stream>>>(hb, rbuf, fb, roff, csr, dinv,
                                        bs + (size_t)l * D,
                                        stats + (size_t)l * 2 * D, N, half);
    }

    k_pool<<<G, 128, 0, stream>>>(fb, goff,
                                  gammas + (size_t)(NLAYERS - 1) * D,
                                  betas + (size_t)(NLAYERS - 1) * D,
                                  stats + (size_t)(NLAYERS - 1) * 2 * D,
                                  invN, out);
}

// Round 15
// 743.264 us; speedup vs baseline: 1.0207x; 1.0207x over previous
//
#include <hip/hip_runtime.h>

#define D 128
#define NLAYERS 3
#define BN_EPS 1e-5f

typedef short bf16x8 __attribute__((ext_vector_type(8)));
typedef float f32x4 __attribute__((ext_vector_type(4)));

__device__ __forceinline__ unsigned short f2bf(float f) {
    unsigned int u = __float_as_uint(f);
    u += 0x7FFFu + ((u >> 16) & 1u);   // round-to-nearest-even
    return (unsigned short)(u >> 16);
}
__device__ __forceinline__ float bf2f(unsigned short b) {
    return __uint_as_float(((unsigned int)b) << 16);
}
__device__ __forceinline__ float bf_lo(unsigned int u) {
    return __uint_as_float(u << 16);
}
__device__ __forceinline__ float bf_hi(unsigned int u) {
    return __uint_as_float(u & 0xFFFF0000u);
}

// ---------------- setup kernels ----------------

// zero cnt + gcnt + stats in one dispatch
__global__ void k_zero(int* __restrict__ cnt, int* __restrict__ gcnt,
                       int* __restrict__ stats, int N, int G, int S) {
    int i = blockIdx.x * blockDim.x + threadIdx.x;
    if (i < N) cnt[i] = 0;
    else if (i < N + G) gcnt[i - N] = 0;
    else if (i < N + G + S) stats[i - N - G] = 0;
}

// merged: edge histogram + batch histogram + x->bf16 convert
__global__ void k_hist_xb(const int* __restrict__ dst, const int* __restrict__ batch,
                          const float* __restrict__ x,
                          int* __restrict__ cnt, int* __restrict__ gcnt,
                          unsigned short* __restrict__ fb, int E, int N, int n8) {
    int i = blockIdx.x * blockDim.x + threadIdx.x;
    if (i < E) {
        atomicAdd(&cnt[dst[i]], 1);
    } else if (i < E + N) {
        atomicAdd(&gcnt[batch[i - E]], 1);
    } else {
        int j = i - E - N;
        if (j < n8) {
            const float4 a = ((const float4*)x)[j * 2];
            const float4 b = ((const float4*)x)[j * 2 + 1];
            uint4 p;
            p.x = (unsigned int)f2bf(a.x) | ((unsigned int)f2bf(a.y) << 16);
            p.y = (unsigned int)f2bf(a.z) | ((unsigned int)f2bf(a.w) << 16);
            p.z = (unsigned int)f2bf(b.x) | ((unsigned int)f2bf(b.y) << 16);
            p.w = (unsigned int)f2bf(b.z) | ((unsigned int)f2bf(b.w) << 16);
            ((uint4*)fb)[j] = p;
        }
    }
}

// partial sums of PADDED counts; also computes dinv and zeroes dummy hb row
__global__ void k_scan_partial(const int* __restrict__ cnt, int* __restrict__ bsum,
                               float* __restrict__ dinv, unsigned short* __restrict__ hb,
                               int N) {
    __shared__ int sh[256];
    int b = blockIdx.x, t = threadIdx.x;
    int base = b * 1024 + t * 4;
    int s = 0;
#pragma unroll
    for (int i = 0; i < 4; ++i) {
        int idx = base + i;
        int cv = (idx < N) ? cnt[idx] : 0;
        if (idx < N) dinv[idx] = rsqrtf((float)(cv + 1));   // +1 self loop
        s += (cv + 3) & ~3;
    }
    if (b == 0 && t < D) hb[(size_t)N * D + t] = 0;
    sh[t] = s;
    for (int ofs = 128; ofs > 0; ofs >>= 1) {
        __syncthreads();
        if (t < ofs) sh[t] += sh[t + ofs];
    }
    __syncthreads();
    if (t == 0) bsum[b] = sh[0];
}

// merged: block 0 = exclusive scan of block sums; block 1 = graph-count scan
__global__ void k_scan_small_g(const int* __restrict__ bsum, int* __restrict__ bbase, int nb,
                               const int* __restrict__ gcnt, int* __restrict__ goff,
                               int G, int N) {
    __shared__ int sh[256];
    int t = threadIdx.x;
    if (blockIdx.x == 0) {
        int v = (t < nb) ? bsum[t] : 0;
        sh[t] = v;
        __syncthreads();
        for (int ofs = 1; ofs < 256; ofs <<= 1) {
            int vv = (t >= ofs) ? sh[t - ofs] : 0;
            __syncthreads();
            sh[t] += vv;
            __syncthreads();
        }
        bbase[t] = sh[t] - v;   // exclusive
    } else {
        int base = t * 4;
        int v[4]; int s = 0;
#pragma unroll
        for (int i = 0; i < 4; ++i) { v[i] = (base + i < G) ? gcnt[base + i] : 0; s += v[i]; }
        sh[t] = s;
        __syncthreads();
        for (int ofs = 1; ofs < 256; ofs <<= 1) {
            int vv = (t >= ofs) ? sh[t - ofs] : 0;
            __syncthreads();
            sh[t] += vv;
            __syncthreads();
        }
        int o = sh[t] - s;
#pragma unroll
        for (int i = 0; i < 4; ++i) {
            int idx = base + i;
            if (idx < G) { goff[idx] = o; o += v[i]; }
        }
        if (t == 255) goff[G] = N;
    }
}

// scan apply; ALSO writes the per-node CSR pad slots (dummy index N)
__global__ void k_scan_apply(const int* __restrict__ cnt, const int* __restrict__ bbase,
                             int* __restrict__ roff, int* __restrict__ cur,
                             int* __restrict__ csr, int N) {
    __shared__ int sh[256];
    int b = blockIdx.x, t = threadIdx.x;
    int base = b * 1024 + t * 4;
    int vr[4], v[4]; int s = 0;
#pragma unroll
    for (int i = 0; i < 4; ++i) {
        int cv = (base + i < N) ? cnt[base + i] : 0;
        vr[i] = cv;
        v[i] = (cv + 3) & ~3;
        s += v[i];
    }
    sh[t] = s;
    __syncthreads();
    for (int ofs = 1; ofs < 256; ofs <<= 1) {
        int vv = (t >= ofs) ? sh[t - ofs] : 0;
        __syncthreads();
        sh[t] += vv;
        __syncthreads();
    }
    int o = bbase[b] + sh[t] - s;
#pragma unroll
    for (int i = 0; i < 4; ++i) {
        int idx = base + i;
        if (idx < N) {
            roff[idx] = o; cur[idx] = o;
            for (int p = vr[i]; p < v[i]; ++p) csr[o + p] = N;   // pads
            o += v[i];
            if (idx == N - 1) roff[N] = o;
        }
    }
}

__global__ void k_fill(const int* __restrict__ src, const int* __restrict__ dst,
                       int* __restrict__ cur, int* __restrict__ csr, int E) {
    int i = blockIdx.x * blockDim.x + threadIdx.x;
    if (i < E) {
        int p = atomicAdd(&cur[dst[i]], 1);
        csr[p] = src[i];
    }
}

// Merged pack + fold + BN-finalize. a/c derived in-kernel from prev stats.
__global__ void k_packfold(const float* __restrict__ W, const float* __restrict__ rW,
                           const float* __restrict__ gam, const float* __restrict__ bet,
                           const float* __restrict__ stats, const float* __restrict__ rb,
                           unsigned short* __restrict__ Wp,
                           float* __restrict__ cwA, float* __restrict__ crb,
                           int first, float invN) {
    if (blockIdx.x < 128) {
        int idx = blockIdx.x * 256 + threadIdx.x;       // 0..32767
        int m = idx >> 14;
        int i = idx & 16383;
        int k = i >> 7, col = i & 127;
        float a = 1.f;
        if (!first) {
            float mean = stats[k] * invN;
            float var = stats[D + k] * invN - mean * mean;
            a = gam[k] * rsqrtf(var + BN_EPS);
        }
        const float* src = m ? rW : W;
        float v = a * src[i];
        int frag = ((k >> 5) << 3) + (col >> 4);
        int lane = (((k & 31) >> 3) << 4) + (col & 15);
        int j = k & 7;
        Wp[(m << 14) + frag * 512 + lane * 8 + j] = f2bf(v);
    } else {
        __shared__ float csh[128];
        int t = threadIdx.x;  // 256
        if (t < D) {
            float c = 0.f;
            if (!first) {
                float mean = stats[t] * invN;
                float var = stats[D + t] * invN - mean * mean;
                float a = gam[t] * rsqrtf(var + BN_EPS);
                c = bet[t] - mean * a;
            }
            csh[t] = c;
        }
        __syncthreads();
        if (t < D) {
            float s = 0.f;
            for (int k = 0; k < D; ++k) s += csh[k] * W[k * D + t];
            cwA[t] = s;
        } else {
            int j = t - D;
            float s = rb[j];
            for (int k = 0; k < D; ++k) s += csh[k] * rW[k * D + j];
            crb[j] = s;
        }
    }
}

// ---------------- MFMA GEMM, 64-row tiles, one GEMM per block ----------------
// blockIdx.y = m: m=0 -> hb = (fb@W0 + add0)*dinv ; m=1 -> rbuf = relu(fb@W1+add1)
__global__ __launch_bounds__(256) void k_gemm_mfma(
    const unsigned short* __restrict__ fb,
    const unsigned short* __restrict__ Wp,    // [2][16384] packed frags
    const float* __restrict__ add0, const float* __restrict__ add1,
    const float* __restrict__ dinv,
    unsigned short* __restrict__ hb, unsigned short* __restrict__ rbuf, int N) {
    __shared__ unsigned short As[64 * 128];    // 16 KB, XOR-swizzled
    __shared__ unsigned short Wb[128 * 128];   // 32 KB, linear frag layout
    const int t = threadIdx.x;
    const int m = blockIdx.y;
    const int rowbase = blockIdx.x * 64;
    const unsigned short* wp = Wp + (m << 14);

#pragma unroll
    for (int i = 0; i < 4; ++i) {
        int ch = t + i * 256;
        int row = ch >> 4, slot = ch & 15;
        uint4 v = make_uint4(0, 0, 0, 0);
        int gr = rowbase + row;
        if (gr < N) v = *(const uint4*)(fb + (size_t)gr * D + slot * 8);
        *(uint4*)((char*)As + row * 256 + ((slot ^ (row & 7)) << 4)) = v;
    }
#pragma unroll
    for (int i = 0; i < 8; ++i) {
        int ch = t + i * 256;
        *(uint4*)((char*)Wb + ch * 16) = *(const uint4*)((const char*)wp + ch * 16);
    }
    __syncthreads();

    const int wave = t >> 6, l = t & 63;
    const int wrow = wave * 16;
    const int lg = l >> 4, lc = l & 15;
    const int n0 = wrow + lc;
    const int g0 = rowbase + n0;
    const int f0 = lg * 4;
    const int half = lg & 1;

    f32x4 acc[8];
#pragma unroll
    for (int cf = 0; cf < 8; ++cf) acc[cf] = (f32x4){0.f, 0.f, 0.f, 0.f};

#pragma unroll
    for (int ks = 0; ks < 4; ++ks) {
        const int s = ks * 4 + lg;
        bf16x8 a0 = *(const bf16x8*)((const char*)As + n0 * 256 + ((s ^ (n0 & 7)) << 4));
#pragma unroll
        for (int cf = 0; cf < 8; ++cf) {
            bf16x8 b = *(const bf16x8*)((const char*)Wb + ((ks * 8 + cf) * 64 + l) * 16);
            acc[cf] = __builtin_amdgcn_mfma_f32_16x16x32_bf16(b, a0, acc[cf], 0, 0, 0);
        }
    }

    __syncthreads();   // As consumed -> reuse as epilogue buffer

    if (m == 0) {
        const float dv0 = (g0 < N) ? dinv[g0] : 0.f;
#pragma unroll
        for (int cf = 0; cf < 8; ++cf) {
            const int fx = cf * 16 + f0;
            const float4 va = *(const float4*)(add0 + fx);
            const int slot = cf * 2 + (lg >> 1);
            uint2 p0;
            p0.x = (unsigned int)f2bf((acc[cf][0] + va.x) * dv0) |
                   ((unsigned int)f2bf((acc[cf][1] + va.y) * dv0) << 16);
            p0.y = (unsigned int)f2bf((acc[cf][2] + va.z) * dv0) |
                   ((unsigned int)f2bf((acc[cf][3] + va.w) * dv0) << 16);
            *(uint2*)((char*)As + n0 * 256 + ((slot ^ (n0 & 7)) << 4) + half * 8) = p0;
        }
    } else {
#pragma unroll
        for (int cf = 0; cf < 8; ++cf) {
            const int fx = cf * 16 + f0;
            const float4 va = *(const float4*)(add1 + fx);
            const int slot = cf * 2 + (lg >> 1);
            uint2 p0;
            p0.x = (unsigned int)f2bf(fmaxf(acc[cf][0] + va.x, 0.f)) |
                   ((unsigned int)f2bf(fmaxf(acc[cf][1] + va.y, 0.f)) << 16);
            p0.y = (unsigned int)f2bf(fmaxf(acc[cf][2] + va.z, 0.f)) |
                   ((unsigned int)f2bf(fmaxf(acc[cf][3] + va.w, 0.f)) << 16);
            *(uint2*)((char*)As + n0 * 256 + ((slot ^ (n0 & 7)) << 4) + half * 8) = p0;
        }
    }

    __syncthreads();

    unsigned short* __restrict__ dstp = (m == 0) ? hb : rbuf;
#pragma unroll
    for (int i = 0; i < 4; ++i) {
        int ch = t + i * 256;
        int row = ch >> 4, sl = ch & 15;
        int gr = rowbase + row;
        if (gr < N) {
            uint4 v = *(const uint4*)((const char*)As + row * 256 + ((sl ^ (row & 7)) << 4));
            *(uint4*)(dstp + (size_t)gr * D + sl * 8) = v;
        }
    }
}

// ---------------- aggregation + residual + BN stats ----------------
// DUAL-NODE x DUAL-QUAD per wave: 4 independent gather-quads in flight per
// iteration. Clamped addresses + select-to-dummy-row guards keep the loop
// wave-uniform. CSR padded to x4 with dummy index N -> zero row.
__global__ __launch_bounds__(256) void k_agg(
    const unsigned short* __restrict__ hb, const unsigned short* __restrict__ resb,
    unsigned short* __restrict__ fbout,
    const int* __restrict__ roff, const int* __restrict__ csr,
    const float* __restrict__ dinv, const float* __restrict__ bias,
    float* __restrict__ stats, int N, int half) {
    const int tid = threadIdx.x;
    const int lane = tid & 63;
    const int g = lane >> 4;           // edge slot within quad
    const int li = lane & 15;          // 16-lane column group
    const int cs = li * 8;             // 8 bf16 columns per lane
    const int wid = (blockIdx.x * blockDim.x + tid) >> 6;
    const int nw = (gridDim.x * blockDim.x) >> 6;

    float bv[8];
#pragma unroll
    for (int k = 0; k < 8; ++k) bv[k] = bias[cs + k];

    float s8[8], q8[8];
#pragma unroll
    for (int k = 0; k < 8; ++k) { s8[k] = 0.f; q8[k] = 0.f; }

    for (int p = wid; p < half; p += nw) {
        const int vA = p;
        const int vB = p + half;
        const bool hasB = (vB < N);
        const int begA = roff[vA];
        const int qA = (roff[vA + 1] - begA) >> 2;
        int begB = begA, qB = 0;
        if (hasB) { begB = roff[vB]; qB = (roff[vB + 1] - begB) >> 2; }

        float accA[8], accB[8];
#pragma unroll
        for (int k = 0; k < 8; ++k) { accA[k] = 0.f; accB[k] = 0.f; }

        const int mq = (qA > qB) ? qA : qB;
        for (int i = 0; i < mq; i += 2) {
            int jA0 = i < qA ? i : (qA - 1); jA0 = jA0 < 0 ? 0 : jA0;
            int jA1 = (i + 1) < qA ? (i + 1) : (qA - 1); jA1 = jA1 < 0 ? 0 : jA1;
            int jB0 = i < qB ? i : (qB - 1); jB0 = jB0 < 0 ? 0 : jB0;
            int jB1 = (i + 1) < qB ? (i + 1) : (qB - 1); jB1 = jB1 < 0 ? 0 : jB1;
            const int4 a40 = *(const int4*)(csr + begA + jA0 * 4);
            const int4 a41 = *(const int4*)(csr + begA + jA1 * 4);
            const int4 b40 = *(const int4*)(csr + begB + jB0 * 4);
            const int4 b41 = *(const int4*)(csr + begB + jB1 * 4);
            int ua0 = (g == 0) ? a40.x : (g == 1) ? a40.y : (g == 2) ? a40.z : a40.w;
            int ua1 = (g == 0) ? a41.x : (g == 1) ? a41.y : (g == 2) ? a41.z : a41.w;
            int ub0 = (g == 0) ? b40.x : (g == 1) ? b40.y : (g == 2) ? b40.z : b40.w;
            int ub1 = (g == 0) ? b41.x : (g == 1) ? b41.y : (g == 2) ? b41.z : b41.w;
            ua0 = (i < qA) ? ua0 : N;
            ua1 = (i + 1 < qA) ? ua1 : N;
            ub0 = (i < qB) ? ub0 : N;
            ub1 = (i + 1 < qB) ? ub1 : N;
            const uint4 ga0 = *(const uint4*)(hb + (size_t)ua0 * D + cs);
            const uint4 ga1 = *(const uint4*)(hb + (size_t)ua1 * D + cs);
            const uint4 gb0 = *(const uint4*)(hb + (size_t)ub0 * D + cs);
            const uint4 gb1 = *(const uint4*)(hb + (size_t)ub1 * D + cs);
            accA[0] += bf_lo(ga0.x) + bf_lo(ga1.x); accA[1] += bf_hi(ga0.x) + bf_hi(ga1.x);
            accA[2] += bf_lo(ga0.y) + bf_lo(ga1.y); accA[3] += bf_hi(ga0.y) + bf_hi(ga1.y);
            accA[4] += bf_lo(ga0.z) + bf_lo(ga1.z); accA[5] += bf_hi(ga0.z) + bf_hi(ga1.z);
            accA[6] += bf_lo(ga0.w) + bf_lo(ga1.w); accA[7] += bf_hi(ga0.w) + bf_hi(ga1.w);
            accB[0] += bf_lo(gb0.x) + bf_lo(gb1.x); accB[1] += bf_hi(gb0.x) + bf_hi(gb1.x);
            accB[2] += bf_lo(gb0.y) + bf_lo(gb1.y); accB[3] += bf_hi(gb0.y) + bf_hi(gb1.y);
            accB[4] += bf_lo(gb0.z) + bf_lo(gb1.z); accB[5] += bf_hi(gb0.z) + bf_hi(gb1.z);
            accB[6] += bf_lo(gb0.w) + bf_lo(gb1.w); accB[7] += bf_hi(gb0.w) + bf_hi(gb1.w);
        }

#pragma unroll
        for (int k = 0; k < 8; ++k) {
            accA[k] += __shfl_xor(accA[k], 16);
            accA[k] += __shfl_xor(accA[k], 32);
            accB[k] += __shfl_xor(accB[k], 16);
            accB[k] += __shfl_xor(accB[k], 32);
        }

        // ---- epilogue node A ----
        {
            const float dv = dinv[vA];
            const uint4 hs = *(const uint4*)(hb + (size_t)vA * D + cs);
            const uint4 rr = *(const uint4*)(resb + (size_t)vA * D + cs);
            float ox[8];
            ox[0] = (accA[0] + bf_lo(hs.x)) * dv + bv[0] + bf_lo(rr.x);
            ox[1] = (accA[1] + bf_hi(hs.x)) * dv + bv[1] + bf_hi(rr.x);
            ox[2] = (accA[2] + bf_lo(hs.y)) * dv + bv[2] + bf_lo(rr.y);
            ox[3] = (accA[3] + bf_hi(hs.y)) * dv + bv[3] + bf_hi(rr.y);
            ox[4] = (accA[4] + bf_lo(hs.z)) * dv + bv[4] + bf_lo(rr.z);
            ox[5] = (accA[5] + bf_hi(hs.z)) * dv + bv[5] + bf_hi(rr.z);
            ox[6] = (accA[6] + bf_lo(hs.w)) * dv + bv[6] + bf_lo(rr.w);
            ox[7] = (accA[7] + bf_hi(hs.w)) * dv + bv[7] + bf_hi(rr.w);
            if (g == 0) {
                uint4 pk;
                pk.x = (unsigned int)f2bf(ox[0]) | ((unsigned int)f2bf(ox[1]) << 16);
                pk.y = (unsigned int)f2bf(ox[2]) | ((unsigned int)f2bf(ox[3]) << 16);
                pk.z = (unsigned int)f2bf(ox[4]) | ((unsigned int)f2bf(ox[5]) << 16);
                pk.w = (unsigned int)f2bf(ox[6]) | ((unsigned int)f2bf(ox[7]) << 16);
                *(uint4*)(fbout + (size_t)vA * D + cs) = pk;
#pragma unroll
                for (int k = 0; k < 8; ++k) { s8[k] += ox[k]; q8[k] += ox[k] * ox[k]; }
            }
        }
        // ---- epilogue node B ----
        if (hasB) {
            const float dv = dinv[vB];
            const uint4 hs = *(const uint4*)(hb + (size_t)vB * D + cs);
            const uint4 rr = *(const uint4*)(resb + (size_t)vB * D + cs);
            float ox[8];
            ox[0] = (accB[0] + bf_lo(hs.x)) * dv + bv[0] + bf_lo(rr.x);
            ox[1] = (accB[1] + bf_hi(hs.x)) * dv + bv[1] + bf_hi(rr.x);
            ox[2] = (accB[2] + bf_lo(hs.y)) * dv + bv[2] + bf_lo(rr.y);
            ox[3] = (accB[3] + bf_hi(hs.y)) * dv + bv[3] + bf_hi(rr.y);
            ox[4] = (accB[4] + bf_lo(hs.z)) * dv + bv[4] + bf_lo(rr.z);
            ox[5] = (accB[5] + bf_hi(hs.z)) * dv + bv[5] + bf_hi(rr.z);
            ox[6] = (accB[6] + bf_lo(hs.w)) * dv + bv[6] + bf_lo(rr.w);
            ox[7] = (accB[7] + bf_hi(hs.w)) * dv + bv[7] + bf_hi(rr.w);
            if (g == 0) {
                uint4 pk;
                pk.x = (unsigned int)f2bf(ox[0]) | ((unsigned int)f2bf(ox[1]) << 16);
                pk.y = (unsigned int)f2bf(ox[2]) | ((unsigned int)f2bf(ox[3]) << 16);
                pk.z = (unsigned int)f2bf(ox[4]) | ((unsigned int)f2bf(ox[5]) << 16);
                pk.w = (unsigned int)f2bf(ox[6]) | ((unsigned int)f2bf(ox[7]) << 16);
                *(uint4*)(fbout + (size_t)vB * D + cs) = pk;
#pragma unroll
                for (int k = 0; k < 8; ++k) { s8[k] += ox[k]; q8[k] += ox[k] * ox[k]; }
            }
        }
    }

    // block-level BN-stats reduction: lanes g==0 hold valid partials
    __shared__ float sred[4][16][8];
    __shared__ float qred[4][16][8];
    const int w = tid >> 6;
    if (g == 0) {
#pragma unroll
        for (int k = 0; k < 8; ++k) { sred[w][li][k] = s8[k]; qred[w][li][k] = q8[k]; }
    }
    __syncthreads();
    if (tid < D) {
        const int col = tid;
        float ts = 0.f, tq = 0.f;
#pragma unroll
        for (int ww = 0; ww < 4; ++ww) {
            ts += sred[ww][col >> 3][col & 7];
            tq += qred[ww][col >> 3][col & 7];
        }
        atomicAdd(&stats[col], ts);
        atomicAdd(&stats[D + col], tq);
    }
}

// pool with embedded final BN: a,c computed per-block from last stats
__global__ void k_pool(const unsigned short* __restrict__ fb, const int* __restrict__ goff,
                       const float* __restrict__ gam, const float* __restrict__ bet,
                       const float* __restrict__ stats, float invN,
                       float* __restrict__ out) {
    int g = blockIdx.x, t = threadIdx.x;  // 128 threads
    float mean = stats[t] * invN;
    float var = stats[D + t] * invN - mean * mean;
    float a = gam[t] * rsqrtf(var + BN_EPS);
    float c = bet[t] - mean * a;
    int beg = goff[g], end = goff[g + 1];
    float acc = 0.f;
    for (int v = beg; v < end; ++v) acc += bf2f(fb[(size_t)v * D + t]);
    out[(size_t)g * D + t] = acc * a + (float)(end - beg) * c;
}

// ---------------- launcher ----------------

extern "C" void kernel_launch(void* const* d_in, const int* in_sizes, int n_in,
                              void* d_out, int out_size, void* d_ws, size_t ws_size,
                              hipStream_t stream) {
    const float* x      = (const float*)d_in[0];
    const int*   ei     = (const int*)d_in[1];
    const int*   batch  = (const int*)d_in[2];
    const float* Ws     = (const float*)d_in[3];
    const float* bs     = (const float*)d_in[4];
    const float* rWs    = (const float*)d_in[5];
    const float* rbs    = (const float*)d_in[6];
    const float* gammas = (const float*)d_in[7];
    const float* betas  = (const float*)d_in[8];
    float* out = (float*)d_out;

    const int N = in_sizes[2];
    const int E = in_sizes[1] / 2;
    const int G = out_size / D;
    const int* src = ei;
    const int* dst = ei + E;
    const int EP = E + 4 * N + 8;   // padded-CSR upper bound (+2 quad guard)
    const int half = (N + 1) >> 1;
    const float invN = 1.0f / (float)N;
    const int n8 = N * (D / 8);

    char* ws = (char*)d_ws;
    size_t off = 0;
    auto alloc = [&](size_t bytes) -> char* {
        char* p = ws + off;
        off += (bytes + 255) & ~(size_t)255;
        return p;
    };
    unsigned short* hb = (unsigned short*)alloc((size_t)(N + 1) * D * 2);
    unsigned short* fb = (unsigned short*)alloc((size_t)N * D * 2);
    unsigned short* rbuf = (unsigned short*)alloc((size_t)N * D * 2);
    int*   csr  = (int*)alloc((size_t)EP * 4);
    int*   roff = (int*)alloc((size_t)(N + 1) * 4);
    int*   cur  = (int*)alloc((size_t)N * 4);
    int*   cnt  = (int*)alloc((size_t)N * 4);
    float* dinv = (float*)alloc((size_t)N * 4);
    int*   gcnt = (int*)alloc((size_t)G * 4);
    int*   goff = (int*)alloc((size_t)(G + 1) * 4);
    int*   bsum = (int*)alloc(256 * 4);
    int*   bbase= (int*)alloc(256 * 4);
    float* stats= (float*)alloc((size_t)NLAYERS * 2 * D * 4);
    unsigned short* Wp = (unsigned short*)alloc((size_t)2 * D * D * 2);
    float* cwA  = (float*)alloc(D * 4);
    float* crb  = (float*)alloc(D * 4);
    (void)ws_size;

    const int S = NLAYERS * 2 * D;
    k_zero<<<(N + G + S + 255) / 256, 256, 0, stream>>>(cnt, gcnt, (int*)stats, N, G, S);
    k_hist_xb<<<(E + N + n8 + 255) / 256, 256, 0, stream>>>(dst, batch, x, cnt, gcnt,
                                                            fb, E, N, n8);

    int nb = (N + 1023) / 1024;
    k_scan_partial<<<nb, 256, 0, stream>>>(cnt, bsum, dinv, hb, N);
    k_scan_small_g<<<2, 256, 0, stream>>>(bsum, bbase, nb, gcnt, goff, G, N);
    k_scan_apply<<<nb, 256, 0, stream>>>(cnt, bbase, roff, cur, csr, N);
    k_fill<<<(E + 255) / 256, 256, 0, stream>>>(src, dst, cur, csr, E);

    dim3 ggrid((N + 63) / 64, 2);
    for (int l = 0; l < NLAYERS; ++l) {
        const float* W  = Ws + (size_t)l * D * D;
        const float* rW = rWs + (size_t)l * D * D;
        const float* gamP = gammas + (size_t)(l > 0 ? l - 1 : 0) * D;
        const float* betP = betas + (size_t)(l > 0 ? l - 1 : 0) * D;
        const float* stP  = stats + (size_t)(l > 0 ? l - 1 : 0) * 2 * D;

        k_packfold<<<129, 256, 0, stream>>>(W, rW, gamP, betP, stP,
                                            rbs + (size_t)l * D,
                                            Wp, cwA, crb, (l == 0) ? 1 : 0, invN);

        k_gemm_mfma<<<ggrid, 256, 0, stream>>>(fb, Wp, cwA, crb, dinv,
                                               hb, rbuf, N);
        k_agg<<<4096, 256, 0, stream>>>(hb, rbuf, fb, roff, csr, dinv,
                                        bs + (size_t)l * D,
                                        stats + (size_t)l * 2 * D, N, half);
    }

    k_pool<<<G, 128, 0, stream>>>(fb, goff,
                                  gammas + (size_t)(NLAYERS - 1) * D,
                                  betas + (size_t)(NLAYERS - 1) * D,
                                  stats + (size_t)(NLAYERS - 1) * 2 * D,
                                  invN, out);
}